// Round 1
// baseline (138.326 us; speedup 1.0000x reference)
//
#include <hip/hip_runtime.h>
#include <hip/hip_bf16.h>

typedef __bf16 bf16_t;
typedef __attribute__((ext_vector_type(8))) __bf16 bf16x8;
typedef __attribute__((ext_vector_type(4))) float f32x4;

#define SEQ    2048
#define DMODEL 1024
#define DPROJ  256
#define NBATCH 4

__device__ __forceinline__ bf16x8 cvt8(const float4& lo, const float4& hi) {
    bf16x8 v;
    v[0] = (bf16_t)lo.x; v[1] = (bf16_t)lo.y; v[2] = (bf16_t)lo.z; v[3] = (bf16_t)lo.w;
    v[4] = (bf16_t)hi.x; v[5] = (bf16_t)hi.y; v[6] = (bf16_t)hi.z; v[7] = (bf16_t)hi.w;
    return v;
}

// Kernel 1: H[m,p] = relu( sum_d X[m,d]*W[p,d] + bias[p] ), H stored bf16.
// M=8192 (B*S flattened), N=DPROJ=256, K=DMODEL=1024. BM=BN=64, BK=32.
__global__ __launch_bounds__(256) void proj_kernel(
    const float* __restrict__ X, const float* __restrict__ W,
    const float* __restrict__ bias, bf16_t* __restrict__ H)
{
    // +8 pad: row stride 80B -> 16B aligned for b128, bank spread 2-way (free)
    __shared__ __align__(16) bf16_t As[64][40];
    __shared__ __align__(16) bf16_t Bs[64][40];

    const int m0 = blockIdx.x * 64;
    const int n0 = blockIdx.y * 64;
    const int tid  = threadIdx.x;
    const int lane = tid & 63;
    const int wave = tid >> 6;
    const int quad = lane >> 4;
    const int l16  = lane & 15;
    const int wm = (wave & 1) * 32;   // wave's 32x32 quadrant
    const int wn = (wave >> 1) * 32;

    const int srow = tid >> 2;        // 0..63 staging row
    const int scol = (tid & 3) * 8;   // 0,8,16,24

    f32x4 acc[2][2] = {};

    for (int k0 = 0; k0 < DMODEL; k0 += 32) {
        const float* ga = X + (size_t)(m0 + srow) * DMODEL + k0 + scol;
        float4 alo = *(const float4*)ga;
        float4 ahi = *(const float4*)(ga + 4);
        const float* gw = W + (size_t)(n0 + srow) * DMODEL + k0 + scol;
        float4 wlo = *(const float4*)gw;
        float4 whi = *(const float4*)(gw + 4);
        __syncthreads();
        *(bf16x8*)&As[srow][scol] = cvt8(alo, ahi);
        *(bf16x8*)&Bs[srow][scol] = cvt8(wlo, whi);
        __syncthreads();
        bf16x8 af[2], bf[2];
        #pragma unroll
        for (int i = 0; i < 2; ++i) {
            af[i] = *(const bf16x8*)&As[wm + i * 16 + l16][quad * 8];
            bf[i] = *(const bf16x8*)&Bs[wn + i * 16 + l16][quad * 8];
        }
        #pragma unroll
        for (int i = 0; i < 2; ++i)
            #pragma unroll
            for (int j = 0; j < 2; ++j)
                acc[i][j] = __builtin_amdgcn_mfma_f32_16x16x32_bf16(
                    af[i], bf[j], acc[i][j], 0, 0, 0);
    }

    #pragma unroll
    for (int i = 0; i < 2; ++i) {
        #pragma unroll
        for (int j = 0; j < 2; ++j) {
            const int gn = n0 + wn + j * 16 + l16;
            const float bv = bias[gn];
            #pragma unroll
            for (int r = 0; r < 4; ++r) {
                const int gm = m0 + wm + i * 16 + quad * 4 + r;
                float v = acc[i][j][r] + bv;
                v = v > 0.f ? v : 0.f;
                H[(size_t)gm * DPROJ + gn] = (bf16_t)v;
            }
        }
    }
}

// Kernel 2: Out[b,i,j] = scale * sum_p H[b,i,p]*H[b,j,p] + off.
// Per batch: M=N=2048, K=256. BM=BN=64, BK=32. Both operands are rows of H.
__global__ __launch_bounds__(256) void score_kernel(
    const bf16_t* __restrict__ H, const float* __restrict__ clf_w,
    const float* __restrict__ clf_b, float* __restrict__ Out)
{
    __shared__ __align__(16) bf16_t As[64][40];
    __shared__ __align__(16) bf16_t Bs[64][40];

    const int b  = blockIdx.z;
    const int m0 = blockIdx.x * 64;
    const int n0 = blockIdx.y * 64;
    const bf16_t* Hb = H + (size_t)b * SEQ * DPROJ;
    float* Ob = Out + (size_t)b * SEQ * SEQ;

    const int tid  = threadIdx.x;
    const int lane = tid & 63;
    const int wave = tid >> 6;
    const int quad = lane >> 4;
    const int l16  = lane & 15;
    const int wm = (wave & 1) * 32;
    const int wn = (wave >> 1) * 32;
    const int srow = tid >> 2;
    const int scol = (tid & 3) * 8;

    f32x4 acc[2][2] = {};

    for (int k0 = 0; k0 < DPROJ; k0 += 32) {
        uint4 av = *(const uint4*)(Hb + (size_t)(m0 + srow) * DPROJ + k0 + scol);
        uint4 bv = *(const uint4*)(Hb + (size_t)(n0 + srow) * DPROJ + k0 + scol);
        __syncthreads();
        *(uint4*)&As[srow][scol] = av;
        *(uint4*)&Bs[srow][scol] = bv;
        __syncthreads();
        bf16x8 af[2], bf[2];
        #pragma unroll
        for (int i = 0; i < 2; ++i) {
            af[i] = *(const bf16x8*)&As[wm + i * 16 + l16][quad * 8];
            bf[i] = *(const bf16x8*)&Bs[wn + i * 16 + l16][quad * 8];
        }
        #pragma unroll
        for (int i = 0; i < 2; ++i)
            #pragma unroll
            for (int j = 0; j < 2; ++j)
                acc[i][j] = __builtin_amdgcn_mfma_f32_16x16x32_bf16(
                    af[i], bf[j], acc[i][j], 0, 0, 0);
    }

    const float scale = clf_w[0];
    const float off   = clf_b[0];
    #pragma unroll
    for (int i = 0; i < 2; ++i)
        #pragma unroll
        for (int j = 0; j < 2; ++j)
            #pragma unroll
            for (int r = 0; r < 4; ++r) {
                const int gm = m0 + wm + i * 16 + quad * 4 + r;
                const int gn = n0 + wn + j * 16 + l16;
                Ob[(size_t)gm * SEQ + gn] = acc[i][j][r] * scale + off;
            }
}

extern "C" void kernel_launch(void* const* d_in, const int* in_sizes, int n_in,
                              void* d_out, int out_size, void* d_ws, size_t ws_size,
                              hipStream_t stream) {
    const float* X    = (const float*)d_in[0];  // [4,2048,1024]
    const float* W    = (const float*)d_in[1];  // [256,1024]
    const float* bias = (const float*)d_in[2];  // [256]
    const float* clfw = (const float*)d_in[3];  // [1,1]
    const float* clfb = (const float*)d_in[4];  // [1]
    float* Out = (float*)d_out;                 // [4,2048,2048]
    bf16_t* H  = (bf16_t*)d_ws;                 // [8192,256] bf16 = 4 MB scratch

    dim3 g1(NBATCH * SEQ / 64, DPROJ / 64, 1);  // 128 x 4
    proj_kernel<<<g1, 256, 0, stream>>>(X, W, bias, H);

    dim3 g2(SEQ / 64, SEQ / 64, NBATCH);        // 32 x 32 x 4
    score_kernel<<<g2, 256, 0, stream>>>(H, clfw, clfb, Out);
}

// Round 2
// 137.622 us; speedup vs baseline: 1.0051x; 1.0051x over previous
//
#include <hip/hip_runtime.h>
#include <hip/hip_bf16.h>

typedef __bf16 bf16_t;
typedef __attribute__((ext_vector_type(8))) __bf16 bf16x8;
typedef __attribute__((ext_vector_type(4))) float f32x4;

#define SEQ    2048
#define DMODEL 1024
#define DPROJ  256
#define NBATCH 4

__device__ __forceinline__ bf16x8 cvt8(const float4& lo, const float4& hi) {
    bf16x8 v;
    v[0] = (bf16_t)lo.x; v[1] = (bf16_t)lo.y; v[2] = (bf16_t)lo.z; v[3] = (bf16_t)lo.w;
    v[4] = (bf16_t)hi.x; v[5] = (bf16_t)hi.y; v[6] = (bf16_t)hi.z; v[7] = (bf16_t)hi.w;
    return v;
}

// async global->LDS, 16 bytes per lane. LDS dest is wave-uniform base + lane*16.
__device__ __forceinline__ void gl_lds16(const void* g, void* l) {
    __builtin_amdgcn_global_load_lds(
        (const __attribute__((address_space(1))) unsigned int*)g,
        (__attribute__((address_space(3))) unsigned int*)l, 16, 0, 0);
}

// ---------------------------------------------------------------------------
// Kernel 1: H[m,p] = relu( sum_d X[m,d]*W[p,d] + bias[p] ), H stored bf16.
// M=8192, N=256, K=1024. BM=64, BN=128, BK=32 -> grid (128,2), X read 2x.
// ---------------------------------------------------------------------------
__global__ __launch_bounds__(256) void proj_kernel(
    const float* __restrict__ X, const float* __restrict__ W,
    const float* __restrict__ bias, bf16_t* __restrict__ H)
{
    // +8 pad: row stride 80B, frag reads land 2 lanes/bank (free)
    __shared__ __align__(16) bf16_t Xs[64][40];
    __shared__ __align__(16) bf16_t Ws[128][40];

    const int m0 = blockIdx.x * 64;
    const int n0 = blockIdx.y * 128;
    const int tid  = threadIdx.x;
    const int lane = tid & 63;
    const int wave = tid >> 6;
    const int quad = lane >> 4;
    const int l16  = lane & 15;
    const int wm = (wave & 1) * 32;   // wave's 32x64 region
    const int wn = (wave >> 1) * 64;

    const int xrow = tid >> 2;        // 64 rows, 8 floats each
    const int xcol = (tid & 3) * 8;
    const int wrow = tid >> 1;        // 128 rows, 16 floats each
    const int wcol = (tid & 1) * 16;

    f32x4 acc[2][4] = {};

    for (int k0 = 0; k0 < DMODEL; k0 += 32) {
        const float* gx = X + (size_t)(m0 + xrow) * DMODEL + k0 + xcol;
        float4 x0 = *(const float4*)gx;
        float4 x1 = *(const float4*)(gx + 4);
        const float* gw = W + (size_t)(n0 + wrow) * DMODEL + k0 + wcol;
        float4 w0 = *(const float4*)gw;
        float4 w1 = *(const float4*)(gw + 4);
        float4 w2 = *(const float4*)(gw + 8);
        float4 w3 = *(const float4*)(gw + 12);
        __syncthreads();
        *(bf16x8*)&Xs[xrow][xcol]     = cvt8(x0, x1);
        *(bf16x8*)&Ws[wrow][wcol]     = cvt8(w0, w1);
        *(bf16x8*)&Ws[wrow][wcol + 8] = cvt8(w2, w3);
        __syncthreads();

        bf16x8 af[2], bfr[4];
        #pragma unroll
        for (int i = 0; i < 2; ++i)
            af[i] = *(const bf16x8*)&Xs[wm + i * 16 + l16][quad * 8];
        #pragma unroll
        for (int j = 0; j < 4; ++j)
            bfr[j] = *(const bf16x8*)&Ws[wn + j * 16 + l16][quad * 8];
        #pragma unroll
        for (int i = 0; i < 2; ++i)
            #pragma unroll
            for (int j = 0; j < 4; ++j)
                acc[i][j] = __builtin_amdgcn_mfma_f32_16x16x32_bf16(
                    af[i], bfr[j], acc[i][j], 0, 0, 0);
    }

    #pragma unroll
    for (int i = 0; i < 2; ++i) {
        #pragma unroll
        for (int j = 0; j < 4; ++j) {
            const int gn = n0 + wn + j * 16 + l16;
            const float bv = bias[gn];
            #pragma unroll
            for (int r = 0; r < 4; ++r) {
                const int gm = m0 + wm + i * 16 + quad * 4 + r;
                float v = acc[i][j][r] + bv;
                v = v > 0.f ? v : 0.f;
                H[(size_t)gm * DPROJ + gn] = (bf16_t)v;
            }
        }
    }
}

// ---------------------------------------------------------------------------
// Kernel 2: Out[b,i,j] = scale * sum_p H[b,i,p]*H[b,j,p] + off.
// Per batch M=N=2048, K=256. BM=BN=128, BK=64, 4 K-tiles.
// m97 structure: global_load_lds width=16 into UNPADDED LDS tiles; bank
// conflicts avoided by XOR-swizzling 16B chunks within each 128B row,
// with the swizzle folded into the per-lane GLOBAL address.
// ---------------------------------------------------------------------------
__global__ __launch_bounds__(256) void score_kernel(
    const bf16_t* __restrict__ H, const float* __restrict__ clf_w,
    const float* __restrict__ clf_b, float* __restrict__ Out)
{
    // 128 rows x 64 cols bf16, linear (row stride 128B), 16KB each
    __shared__ __align__(16) bf16_t As[128 * 64];
    __shared__ __align__(16) bf16_t Bs[128 * 64];

    const int b  = blockIdx.z;
    const int m0 = blockIdx.x * 128;
    const int n0 = blockIdx.y * 128;
    const bf16_t* Hb = H + (size_t)b * SEQ * DPROJ;
    float* Ob = Out + (size_t)b * SEQ * SEQ;

    const int tid  = threadIdx.x;
    const int lane = tid & 63;
    const int wave = tid >> 6;
    const int quad = lane >> 4;
    const int l16  = lane & 15;
    const int wm = (wave & 1) * 64;   // wave's 64x64 region
    const int wn = (wave >> 1) * 64;
    const int swz = l16 & 7;          // = row&7 for all fragment rows

    // Staging plan: chunk id g = (wave*4+t)*64 + lane; row = g>>3, c = g&7.
    // LDS chunk (row,c) stores global chunk c ^ (row&7) of that row.
    const bf16_t* gA[4];
    const bf16_t* gB[4];
    bf16_t* lA[4];
    bf16_t* lB[4];
    #pragma unroll
    for (int t = 0; t < 4; ++t) {
        const int g   = (wave * 4 + t) * 64 + lane;
        const int row = g >> 3;
        const int gc  = (g & 7) ^ (row & 7);
        gA[t] = Hb + (size_t)(m0 + row) * DPROJ + gc * 8;
        gB[t] = Hb + (size_t)(n0 + row) * DPROJ + gc * 8;
        lA[t] = As + (wave * 4 + t) * 512;   // 512 bf16 = 1KB per wave-instr
        lB[t] = Bs + (wave * 4 + t) * 512;
    }

    f32x4 acc[4][4] = {};

    for (int kt = 0; kt < 4; ++kt) {
        __syncthreads();                       // prev tile's reads done
        #pragma unroll
        for (int t = 0; t < 4; ++t) {
            gl_lds16(gA[t], lA[t]);
            gl_lds16(gB[t], lB[t]);
        }
        __syncthreads();                       // drains vmcnt -> data visible
        #pragma unroll
        for (int t = 0; t < 4; ++t) { gA[t] += 64; gB[t] += 64; }

        #pragma unroll
        for (int s = 0; s < 2; ++s) {
            const int ch = ((s * 4 + quad) ^ swz) * 8;
            bf16x8 af[4], bfr[4];
            #pragma unroll
            for (int i = 0; i < 4; ++i)
                af[i] = *(const bf16x8*)&As[(wm + i * 16 + l16) * 64 + ch];
            #pragma unroll
            for (int j = 0; j < 4; ++j)
                bfr[j] = *(const bf16x8*)&Bs[(wn + j * 16 + l16) * 64 + ch];
            #pragma unroll
            for (int i = 0; i < 4; ++i)
                #pragma unroll
                for (int j = 0; j < 4; ++j)
                    acc[i][j] = __builtin_amdgcn_mfma_f32_16x16x32_bf16(
                        af[i], bfr[j], acc[i][j], 0, 0, 0);
        }
    }

    const float scale = clf_w[0];
    const float off   = clf_b[0];
    #pragma unroll
    for (int i = 0; i < 4; ++i)
        #pragma unroll
        for (int j = 0; j < 4; ++j)
            #pragma unroll
            for (int r = 0; r < 4; ++r) {
                const int gm = m0 + wm + i * 16 + quad * 4 + r;
                const int gn = n0 + wn + j * 16 + l16;
                Ob[(size_t)gm * SEQ + gn] = acc[i][j][r] * scale + off;
            }
}

extern "C" void kernel_launch(void* const* d_in, const int* in_sizes, int n_in,
                              void* d_out, int out_size, void* d_ws, size_t ws_size,
                              hipStream_t stream) {
    const float* X    = (const float*)d_in[0];  // [4,2048,1024]
    const float* W    = (const float*)d_in[1];  // [256,1024]
    const float* bias = (const float*)d_in[2];  // [256]
    const float* clfw = (const float*)d_in[3];  // [1,1]
    const float* clfb = (const float*)d_in[4];  // [1]
    float* Out = (float*)d_out;                 // [4,2048,2048]
    bf16_t* H  = (bf16_t*)d_ws;                 // [8192,256] bf16 = 4 MB scratch

    dim3 g1(NBATCH * SEQ / 64, DPROJ / 128, 1); // 128 x 2
    proj_kernel<<<g1, 256, 0, stream>>>(X, W, bias, H);

    dim3 g2(SEQ / 128, SEQ / 128, NBATCH);      // 16 x 16 x 4
    score_kernel<<<g2, 256, 0, stream>>>(H, clfw, clfb, Out);
}

// Round 3
// 130.976 us; speedup vs baseline: 1.0561x; 1.0507x over previous
//
#include <hip/hip_runtime.h>
#include <hip/hip_bf16.h>

typedef __bf16 bf16_t;
typedef __attribute__((ext_vector_type(8))) __bf16 bf16x8;
typedef __attribute__((ext_vector_type(4))) float f32x4;

#define SEQ    2048
#define DMODEL 1024
#define DPROJ  256
#define NBATCH 4

__device__ __forceinline__ bf16x8 cvt8(const float4& lo, const float4& hi) {
    bf16x8 v;
    v[0] = (bf16_t)lo.x; v[1] = (bf16_t)lo.y; v[2] = (bf16_t)lo.z; v[3] = (bf16_t)lo.w;
    v[4] = (bf16_t)hi.x; v[5] = (bf16_t)hi.y; v[6] = (bf16_t)hi.z; v[7] = (bf16_t)hi.w;
    return v;
}

// async global->LDS, 16 bytes per lane. LDS dest = wave-uniform base + lane*16.
__device__ __forceinline__ void gl_lds16(const void* g, void* l) {
    __builtin_amdgcn_global_load_lds(
        (const __attribute__((address_space(1))) unsigned int*)g,
        (__attribute__((address_space(3))) unsigned int*)l, 16, 0, 0);
}

// ---------------------------------------------------------------------------
// Kernel 1: H[m,p] = relu( sum_d X[m,d]*W[p,d] + bias[p] ), H stored bf16.
// M=8192, N=256, K=1024. BM=BN=64, BK=64 -> grid (128,4)=512 blocks
// (2 blocks/CU), 16 K-iters, VGPR-prefetch pipeline, XOR-swizzled LDS.
// ---------------------------------------------------------------------------
__global__ __launch_bounds__(256) void proj_kernel(
    const float* __restrict__ X, const float* __restrict__ W,
    const float* __restrict__ bias, bf16_t* __restrict__ H)
{
    // unpadded 64x64 bf16 tiles (8 KB each); 16B-chunk XOR swizzle per row
    __shared__ __align__(16) bf16_t Xs[64 * 64];
    __shared__ __align__(16) bf16_t Ws[64 * 64];

    const int m0 = blockIdx.x * 64;
    const int n0 = blockIdx.y * 64;
    const int tid  = threadIdx.x;
    const int lane = tid & 63;
    const int wave = tid >> 6;
    const int quad = lane >> 4;
    const int l16  = lane & 15;
    const int wm = (wave & 1) * 32;
    const int wn = (wave >> 1) * 32;
    const int swz = l16 & 7;

    // staging: chunk-pair p = r*256 + tid (r=0,1): row = p>>3, c = p&7
    // (8 fp32 = one bf16x8 chunk). LDS col chunk = c ^ (row&7).
    int srow[2], scol[2];
    bf16_t* lx[2];
    bf16_t* lw[2];
    #pragma unroll
    for (int r = 0; r < 2; ++r) {
        const int p = r * 256 + tid;
        srow[r] = p >> 3;
        scol[r] = p & 7;
        const int cs = (scol[r] ^ (srow[r] & 7)) * 8;
        lx[r] = Xs + srow[r] * 64 + cs;
        lw[r] = Ws + srow[r] * 64 + cs;
    }

    float4 xr[2][2], wr[2][2];
    #pragma unroll
    for (int r = 0; r < 2; ++r) {
        const float* gx = X + (size_t)(m0 + srow[r]) * DMODEL + scol[r] * 8;
        xr[r][0] = *(const float4*)gx;
        xr[r][1] = *(const float4*)(gx + 4);
        const float* gw = W + (size_t)(n0 + srow[r]) * DMODEL + scol[r] * 8;
        wr[r][0] = *(const float4*)gw;
        wr[r][1] = *(const float4*)(gw + 4);
    }

    f32x4 acc[2][2] = {};

    for (int kt = 0; kt < 16; ++kt) {
        __syncthreads();                 // previous iter's ds_reads done
        #pragma unroll
        for (int r = 0; r < 2; ++r) {
            *(bf16x8*)lx[r] = cvt8(xr[r][0], xr[r][1]);
            *(bf16x8*)lw[r] = cvt8(wr[r][0], wr[r][1]);
        }
        __syncthreads();                 // tile visible

        if (kt < 15) {                   // prefetch next tile (in flight during compute)
            const int k0 = (kt + 1) * 64;
            #pragma unroll
            for (int r = 0; r < 2; ++r) {
                const float* gx = X + (size_t)(m0 + srow[r]) * DMODEL + k0 + scol[r] * 8;
                xr[r][0] = *(const float4*)gx;
                xr[r][1] = *(const float4*)(gx + 4);
                const float* gw = W + (size_t)(n0 + srow[r]) * DMODEL + k0 + scol[r] * 8;
                wr[r][0] = *(const float4*)gw;
                wr[r][1] = *(const float4*)(gw + 4);
            }
        }

        #pragma unroll
        for (int ks = 0; ks < 2; ++ks) {
            bf16x8 af[2], bfr[2];
            #pragma unroll
            for (int i = 0; i < 2; ++i) {
                const int ch = (((ks << 2) | quad) ^ swz) * 8;
                af[i]  = *(const bf16x8*)&Xs[(wm + i * 16 + l16) * 64 + ch];
                bfr[i] = *(const bf16x8*)&Ws[(wn + i * 16 + l16) * 64 + ch];
            }
            #pragma unroll
            for (int i = 0; i < 2; ++i)
                #pragma unroll
                for (int j = 0; j < 2; ++j)
                    acc[i][j] = __builtin_amdgcn_mfma_f32_16x16x32_bf16(
                        af[i], bfr[j], acc[i][j], 0, 0, 0);
        }
    }

    #pragma unroll
    for (int i = 0; i < 2; ++i) {
        #pragma unroll
        for (int j = 0; j < 2; ++j) {
            const int gn = n0 + wn + j * 16 + l16;
            const float bv = bias[gn];
            #pragma unroll
            for (int r = 0; r < 4; ++r) {
                const int gm = m0 + wm + i * 16 + quad * 4 + r;
                float v = acc[i][j][r] + bv;
                v = v > 0.f ? v : 0.f;
                H[(size_t)gm * DPROJ + gn] = (bf16_t)v;
            }
        }
    }
}

// ---------------------------------------------------------------------------
// Kernel 2: Out[b,i,j] = scale * sum_p H[b,i,p]*H[b,j,p] + off.
// Per batch M=N=2048, K=256. BM=BN=128, BK=64, 4 K-tiles.
// 512 threads = 8 waves, each wave a 32x64 quadrant (acc 2x4, 32 VGPR)
// -> ~24 waves/CU resident to hide the vmcnt(0) barrier drains.
// global_load_lds w=16 into unpadded LDS; XOR swizzle folded into the
// per-lane GLOBAL address.
// ---------------------------------------------------------------------------
__global__ __launch_bounds__(512) void score_kernel(
    const bf16_t* __restrict__ H, const float* __restrict__ clf_w,
    const float* __restrict__ clf_b, float* __restrict__ Out)
{
    __shared__ __align__(16) bf16_t As[128 * 64];   // 16 KB
    __shared__ __align__(16) bf16_t Bs[128 * 64];   // 16 KB

    const int b  = blockIdx.z;
    const int m0 = blockIdx.x * 128;
    const int n0 = blockIdx.y * 128;
    const bf16_t* Hb = H + (size_t)b * SEQ * DPROJ;
    float* Ob = Out + (size_t)b * SEQ * SEQ;

    const int tid  = threadIdx.x;
    const int lane = tid & 63;
    const int wave = tid >> 6;
    const int quad = lane >> 4;
    const int l16  = lane & 15;
    const int wm = (wave & 3) * 32;   // 4 row-quadrants
    const int wn = (wave >> 2) * 64;  // 2 col-halves
    const int swz = l16 & 7;

    // staging: 1024 16B chunks per matrix; instr t in {0,1}:
    // g = (wave*2+t)*64 + lane; row = g>>3, stored chunk = (g&7)^(row&7)
    const bf16_t* gA[2];
    const bf16_t* gB[2];
    bf16_t* lA[2];
    bf16_t* lB[2];
    #pragma unroll
    for (int t = 0; t < 2; ++t) {
        const int g   = (wave * 2 + t) * 64 + lane;
        const int row = g >> 3;
        const int gc  = (g & 7) ^ (row & 7);
        gA[t] = Hb + (size_t)(m0 + row) * DPROJ + gc * 8;
        gB[t] = Hb + (size_t)(n0 + row) * DPROJ + gc * 8;
        lA[t] = As + (wave * 2 + t) * 512;
        lB[t] = Bs + (wave * 2 + t) * 512;
    }

    f32x4 acc[2][4] = {};

    for (int kt = 0; kt < 4; ++kt) {
        __syncthreads();
        #pragma unroll
        for (int t = 0; t < 2; ++t) {
            gl_lds16(gA[t], lA[t]);
            gl_lds16(gB[t], lB[t]);
        }
        __syncthreads();               // drains vmcnt -> data visible
        #pragma unroll
        for (int t = 0; t < 2; ++t) { gA[t] += 64; gB[t] += 64; }

        #pragma unroll
        for (int ks = 0; ks < 2; ++ks) {
            const int ch = (((ks << 2) | quad) ^ swz) * 8;
            bf16x8 af[2], bfr[4];
            #pragma unroll
            for (int i = 0; i < 2; ++i)
                af[i] = *(const bf16x8*)&As[(wm + i * 16 + l16) * 64 + ch];
            #pragma unroll
            for (int j = 0; j < 4; ++j)
                bfr[j] = *(const bf16x8*)&Bs[(wn + j * 16 + l16) * 64 + ch];
            #pragma unroll
            for (int i = 0; i < 2; ++i)
                #pragma unroll
                for (int j = 0; j < 4; ++j)
                    acc[i][j] = __builtin_amdgcn_mfma_f32_16x16x32_bf16(
                        af[i], bfr[j], acc[i][j], 0, 0, 0);
        }
    }

    const float scale = clf_w[0];
    const float off   = clf_b[0];
    #pragma unroll
    for (int i = 0; i < 2; ++i)
        #pragma unroll
        for (int j = 0; j < 4; ++j)
            #pragma unroll
            for (int r = 0; r < 4; ++r) {
                const int gm = m0 + wm + i * 16 + quad * 4 + r;
                const int gn = n0 + wn + j * 16 + l16;
                Ob[(size_t)gm * SEQ + gn] = acc[i][j][r] * scale + off;
            }
}

extern "C" void kernel_launch(void* const* d_in, const int* in_sizes, int n_in,
                              void* d_out, int out_size, void* d_ws, size_t ws_size,
                              hipStream_t stream) {
    const float* X    = (const float*)d_in[0];  // [4,2048,1024]
    const float* W    = (const float*)d_in[1];  // [256,1024]
    const float* bias = (const float*)d_in[2];  // [256]
    const float* clfw = (const float*)d_in[3];  // [1,1]
    const float* clfb = (const float*)d_in[4];  // [1]
    float* Out = (float*)d_out;                 // [4,2048,2048]
    bf16_t* H  = (bf16_t*)d_ws;                 // [8192,256] bf16 = 4 MB scratch

    dim3 g1(NBATCH * SEQ / 64, DPROJ / 64, 1);  // 128 x 4 = 512 blocks
    proj_kernel<<<g1, 256, 0, stream>>>(X, W, bias, H);

    dim3 g2(SEQ / 128, SEQ / 128, NBATCH);      // 16 x 16 x 4 = 1024 blocks
    score_kernel<<<g2, 512, 0, stream>>>(H, clfw, clfb, Out);
}

// Round 4
// 123.721 us; speedup vs baseline: 1.1180x; 1.0586x over previous
//
#include <hip/hip_runtime.h>
#include <hip/hip_bf16.h>

typedef __bf16 bf16_t;
typedef __attribute__((ext_vector_type(8))) __bf16 bf16x8;
typedef __attribute__((ext_vector_type(4))) float f32x4;

#define SEQ    2048
#define DMODEL 1024
#define DPROJ  256
#define NBATCH 4

__device__ __forceinline__ bf16x8 cvt8(const float4& lo, const float4& hi) {
    bf16x8 v;
    v[0] = (bf16_t)lo.x; v[1] = (bf16_t)lo.y; v[2] = (bf16_t)lo.z; v[3] = (bf16_t)lo.w;
    v[4] = (bf16_t)hi.x; v[5] = (bf16_t)hi.y; v[6] = (bf16_t)hi.z; v[7] = (bf16_t)hi.w;
    return v;
}

// async global->LDS, 16 bytes per lane. LDS dest = wave-uniform base + lane*16.
__device__ __forceinline__ void gl_lds16(const void* g, void* l) {
    __builtin_amdgcn_global_load_lds(
        (const __attribute__((address_space(1))) unsigned int*)g,
        (__attribute__((address_space(3))) unsigned int*)l, 16, 0, 0);
}

// ---------------------------------------------------------------------------
// Kernel 1: H[m,p] = relu( sum_d X[m,d]*W[p,d] + bias[p] ), H stored bf16.
// M=8192, N=256, K=1024. BM=BN=64, BK=64, grid 512 (2 blocks/CU).
// Distance-2 VGPR prefetch: loads for tile kt+2 in flight while computing
// tile kt -> ~2 iters of compute to cover ~900cyc HBM latency.
// ---------------------------------------------------------------------------
__global__ __launch_bounds__(256) void proj_kernel(
    const float* __restrict__ X, const float* __restrict__ W,
    const float* __restrict__ bias, bf16_t* __restrict__ H)
{
    __shared__ __align__(16) bf16_t Xs[64 * 64];
    __shared__ __align__(16) bf16_t Ws[64 * 64];

    const int m0 = blockIdx.x * 64;
    const int n0 = blockIdx.y * 64;
    const int tid  = threadIdx.x;
    const int lane = tid & 63;
    const int wave = tid >> 6;
    const int quad = lane >> 4;
    const int l16  = lane & 15;
    const int wm = (wave & 1) * 32;
    const int wn = (wave >> 1) * 32;
    const int swz = l16 & 7;

    int srow[2], scol[2];
    bf16_t* lx[2];
    bf16_t* lw[2];
    #pragma unroll
    for (int r = 0; r < 2; ++r) {
        const int p = r * 256 + tid;
        srow[r] = p >> 3;
        scol[r] = p & 7;
        const int cs = (scol[r] ^ (srow[r] & 7)) * 8;
        lx[r] = Xs + srow[r] * 64 + cs;
        lw[r] = Ws + srow[r] * 64 + cs;
    }

    float4 xr[2][2][2], wr[2][2][2];   // [stage][r][half]

    #pragma unroll
    for (int s = 0; s < 2; ++s) {
        const int k0 = s * 64;
        #pragma unroll
        for (int r = 0; r < 2; ++r) {
            const float* gx = X + (size_t)(m0 + srow[r]) * DMODEL + k0 + scol[r] * 8;
            xr[s][r][0] = *(const float4*)gx;
            xr[s][r][1] = *(const float4*)(gx + 4);
            const float* gw = W + (size_t)(n0 + srow[r]) * DMODEL + k0 + scol[r] * 8;
            wr[s][r][0] = *(const float4*)gw;
            wr[s][r][1] = *(const float4*)(gw + 4);
        }
    }

    f32x4 acc[2][2] = {};

    #pragma unroll
    for (int kt = 0; kt < 16; ++kt) {
        const int s = kt & 1;
        __syncthreads();                 // previous iter's ds_reads done
        #pragma unroll
        for (int r = 0; r < 2; ++r) {
            *(bf16x8*)lx[r] = cvt8(xr[s][r][0], xr[s][r][1]);
            *(bf16x8*)lw[r] = cvt8(wr[s][r][0], wr[s][r][1]);
        }
        __syncthreads();                 // tile visible

        if (kt < 14) {                   // prefetch tile kt+2 into stage s
            const int k0 = (kt + 2) * 64;
            #pragma unroll
            for (int r = 0; r < 2; ++r) {
                const float* gx = X + (size_t)(m0 + srow[r]) * DMODEL + k0 + scol[r] * 8;
                xr[s][r][0] = *(const float4*)gx;
                xr[s][r][1] = *(const float4*)(gx + 4);
                const float* gw = W + (size_t)(n0 + srow[r]) * DMODEL + k0 + scol[r] * 8;
                wr[s][r][0] = *(const float4*)gw;
                wr[s][r][1] = *(const float4*)(gw + 4);
            }
        }

        #pragma unroll
        for (int ks = 0; ks < 2; ++ks) {
            bf16x8 af[2], bfr[2];
            #pragma unroll
            for (int i = 0; i < 2; ++i) {
                const int ch = (((ks << 2) | quad) ^ swz) * 8;
                af[i]  = *(const bf16x8*)&Xs[(wm + i * 16 + l16) * 64 + ch];
                bfr[i] = *(const bf16x8*)&Ws[(wn + i * 16 + l16) * 64 + ch];
            }
            #pragma unroll
            for (int i = 0; i < 2; ++i)
                #pragma unroll
                for (int j = 0; j < 2; ++j)
                    acc[i][j] = __builtin_amdgcn_mfma_f32_16x16x32_bf16(
                        af[i], bfr[j], acc[i][j], 0, 0, 0);
        }
    }

    #pragma unroll
    for (int i = 0; i < 2; ++i) {
        #pragma unroll
        for (int j = 0; j < 2; ++j) {
            const int gn = n0 + wn + j * 16 + l16;
            const float bv = bias[gn];
            #pragma unroll
            for (int r = 0; r < 4; ++r) {
                const int gm = m0 + wm + i * 16 + quad * 4 + r;
                float v = acc[i][j][r] + bv;
                v = v > 0.f ? v : 0.f;
                H[(size_t)gm * DPROJ + gn] = (bf16_t)v;
            }
        }
    }
}

// ---------------------------------------------------------------------------
// Kernel 2: Out[b,i,j] = scale * sum_p H[b,i,p]*H[b,j,p] + off.
// SYMMETRIC: only upper-triangle 128x128 blocks (bi<=bj), 136/batch.
// Each block writes its tile direct AND (off-diagonal) transposed into the
// mirror tile — acc[i][j] (4 consecutive rows, one col) is a ready-made
// float4 along the transposed row. Halves MFMA work; writes unchanged.
// ---------------------------------------------------------------------------
__global__ __launch_bounds__(512) void score_kernel(
    const bf16_t* __restrict__ H, const float* __restrict__ clf_w,
    const float* __restrict__ clf_b, float* __restrict__ Out)
{
    __shared__ __align__(16) bf16_t As[128 * 64];   // 16 KB
    __shared__ __align__(16) bf16_t Bs[128 * 64];   // 16 KB

    // triangular decode: blockIdx.x in [0,136) -> (bi,bj), bi<=bj
    int t = blockIdx.x, bi = 0, rl = SEQ / 128;
    while (t >= rl) { t -= rl; --rl; ++bi; }
    const int bj = bi + t;
    const int b  = blockIdx.y;
    const int m0 = bi * 128;
    const int n0 = bj * 128;
    const bf16_t* Hb = H + (size_t)b * SEQ * DPROJ;
    float* Ob = Out + (size_t)b * SEQ * SEQ;

    const int tid  = threadIdx.x;
    const int lane = tid & 63;
    const int wave = tid >> 6;
    const int quad = lane >> 4;
    const int l16  = lane & 15;
    const int wm = (wave & 3) * 32;   // 4 row-quadrants
    const int wn = (wave >> 2) * 64;  // 2 col-halves
    const int swz = l16 & 7;

    const bf16_t* gA[2];
    const bf16_t* gB[2];
    bf16_t* lA[2];
    bf16_t* lB[2];
    #pragma unroll
    for (int t2 = 0; t2 < 2; ++t2) {
        const int g   = (wave * 2 + t2) * 64 + lane;
        const int row = g >> 3;
        const int gc  = (g & 7) ^ (row & 7);
        gA[t2] = Hb + (size_t)(m0 + row) * DPROJ + gc * 8;
        gB[t2] = Hb + (size_t)(n0 + row) * DPROJ + gc * 8;
        lA[t2] = As + (wave * 2 + t2) * 512;
        lB[t2] = Bs + (wave * 2 + t2) * 512;
    }

    f32x4 acc[2][4] = {};

    for (int kt = 0; kt < 4; ++kt) {
        __syncthreads();
        #pragma unroll
        for (int t2 = 0; t2 < 2; ++t2) {
            gl_lds16(gA[t2], lA[t2]);
            gl_lds16(gB[t2], lB[t2]);
        }
        __syncthreads();               // drains vmcnt -> data visible
        #pragma unroll
        for (int t2 = 0; t2 < 2; ++t2) { gA[t2] += 64; gB[t2] += 64; }

        #pragma unroll
        for (int ks = 0; ks < 2; ++ks) {
            const int ch = (((ks << 2) | quad) ^ swz) * 8;
            bf16x8 af[2], bfr[4];
            #pragma unroll
            for (int i = 0; i < 2; ++i)
                af[i] = *(const bf16x8*)&As[(wm + i * 16 + l16) * 64 + ch];
            #pragma unroll
            for (int j = 0; j < 4; ++j)
                bfr[j] = *(const bf16x8*)&Bs[(wn + j * 16 + l16) * 64 + ch];
            #pragma unroll
            for (int i = 0; i < 2; ++i)
                #pragma unroll
                for (int j = 0; j < 4; ++j)
                    acc[i][j] = __builtin_amdgcn_mfma_f32_16x16x32_bf16(
                        af[i], bfr[j], acc[i][j], 0, 0, 0);
        }
    }

    const float scale = clf_w[0];
    const float off   = clf_b[0];

    // direct tile (bi,bj)
    #pragma unroll
    for (int i = 0; i < 2; ++i)
        #pragma unroll
        for (int j = 0; j < 4; ++j)
            #pragma unroll
            for (int r = 0; r < 4; ++r) {
                const int gm = m0 + wm + i * 16 + quad * 4 + r;
                const int gn = n0 + wn + j * 16 + l16;
                Ob[(size_t)gm * SEQ + gn] = acc[i][j][r] * scale + off;
            }

    // mirror tile (bj,bi): row gn, 4 consecutive cols gm -> float4 store
    if (bi != bj) {
        #pragma unroll
        for (int i = 0; i < 2; ++i)
            #pragma unroll
            for (int j = 0; j < 4; ++j) {
                const int gn = n0 + wn + j * 16 + l16;
                const int gm = m0 + wm + i * 16 + quad * 4;
                float4 v;
                v.x = acc[i][j][0] * scale + off;
                v.y = acc[i][j][1] * scale + off;
                v.z = acc[i][j][2] * scale + off;
                v.w = acc[i][j][3] * scale + off;
                *(float4*)&Ob[(size_t)gn * SEQ + gm] = v;
            }
    }
}

extern "C" void kernel_launch(void* const* d_in, const int* in_sizes, int n_in,
                              void* d_out, int out_size, void* d_ws, size_t ws_size,
                              hipStream_t stream) {
    const float* X    = (const float*)d_in[0];  // [4,2048,1024]
    const float* W    = (const float*)d_in[1];  // [256,1024]
    const float* bias = (const float*)d_in[2];  // [256]
    const float* clfw = (const float*)d_in[3];  // [1,1]
    const float* clfb = (const float*)d_in[4];  // [1]
    float* Out = (float*)d_out;                 // [4,2048,2048]
    bf16_t* H  = (bf16_t*)d_ws;                 // [8192,256] bf16 = 4 MB scratch

    dim3 g1(NBATCH * SEQ / 64, DPROJ / 64, 1);  // 128 x 4 = 512 blocks
    proj_kernel<<<g1, 256, 0, stream>>>(X, W, bias, H);

    const int ntile = SEQ / 128;                // 16
    dim3 g2(ntile * (ntile + 1) / 2, NBATCH);   // 136 x 4 = 544 blocks
    score_kernel<<<g2, 512, 0, stream>>>(H, clfw, clfb, Out);
}